// Round 9
// baseline (377.119 us; speedup 1.0000x reference)
//
#include <hip/hip_runtime.h>

typedef float  f32x4 __attribute__((ext_vector_type(4)));
typedef short  s16x8 __attribute__((ext_vector_type(8)));
typedef unsigned short u16x8 __attribute__((ext_vector_type(8)));

#define NROWS 4096
#define ALPHA_LR 0.2f
#define SCALE 0.0625f
#define NCHUNK 8
#define CHJ 512

static __device__ __forceinline__ unsigned short bf16_rne(float x) {
    unsigned u = __float_as_uint(x);
    u += 0x7fffu + ((u >> 16) & 1u);
    return (unsigned short)(u >> 16);
}
static __device__ __forceinline__ unsigned short bf16_trunc(float x) {
    return (unsigned short)(__float_as_uint(x) >> 16);
}
static __device__ __forceinline__ float bf2f(unsigned short h) {
    return __uint_as_float(((unsigned)h) << 16);
}
static __device__ __forceinline__ float bflo(unsigned u) { return __uint_as_float(u << 16); }
static __device__ __forceinline__ float bfhi(unsigned u) { return __uint_as_float(u & 0xffff0000u); }
static __device__ __forceinline__ float wmax16(float v) {
#pragma unroll
    for (int o = 8; o; o >>= 1) v = fmaxf(v, __shfl_xor(v, o, 16));
    return v;
}
static __device__ __forceinline__ float wsum16(float v) {
#pragma unroll
    for (int o = 8; o; o >>= 1) v += __shfl_xor(v, o, 16);
    return v;
}

// ---------------------------------------------------------------------------
// Convert W (512x256) and Wqkv_w (768x256) to bf16 hi/lo.
// ---------------------------------------------------------------------------
__global__ __launch_bounds__(256) void wprep(
    const float* __restrict__ W, const float* __restrict__ Wq,
    unsigned short* __restrict__ Whi, unsigned short* __restrict__ Wlo,
    unsigned short* __restrict__ Qhi, unsigned short* __restrict__ Qlo)
{
    int i = blockIdx.x * 256 + threadIdx.x;
    if (i < 131072) {
        float v = W[i];
        unsigned short hh = bf16_trunc(v);
        Whi[i] = hh; Wlo[i] = bf16_rne(v - bf2f(hh));
    }
    if (i < 196608) {
        float v = Wq[i];
        unsigned short hh = bf16_trunc(v);
        Qhi[i] = hh; Qlo[i] = bf16_rne(v - bf2f(hh));
    }
}

// ---------------------------------------------------------------------------
// MFMA GEMM, 3-term bf16 hi/lo split (unchanged).
// ---------------------------------------------------------------------------
template <int EPI, bool BIAS>
__global__ __launch_bounds__(256) void gemm_mfma(
    const float* __restrict__ A,
    const unsigned short* __restrict__ Bhi, const unsigned short* __restrict__ Blo,
    const float* __restrict__ bias,
    float* __restrict__ C, unsigned short* __restrict__ o0,
    unsigned short* __restrict__ o1, unsigned short* __restrict__ o2,
    int M, int Nn, int K)
{
    __shared__ unsigned short Ah[64][40];
    __shared__ unsigned short Al[64][40];
    __shared__ unsigned short Bh[64][40];
    __shared__ unsigned short Bl[64][40];

    const int tid = threadIdx.x;
    const int w = tid >> 6;
    const int ln = tid & 63;
    const int l15 = ln & 15;
    const int lhi = ln >> 4;
    const int bm = blockIdx.y * 64;
    const int bn = blockIdx.x * 64;
    const int sm = tid >> 2;
    const int sk = (tid & 3) * 8;

    f32x4 acc[4];
#pragma unroll
    for (int cf = 0; cf < 4; ++cf) acc[cf] = (f32x4){0.f, 0.f, 0.f, 0.f};

    const float* arow = &A[(size_t)(bm + sm) * K];
    const unsigned short* bhrow = &Bhi[(size_t)(bn + sm) * K];
    const unsigned short* blrow = &Blo[(size_t)(bn + sm) * K];

    float4 a0r = *(const float4*)(arow + sk);
    float4 a1r = *(const float4*)(arow + sk + 4);
    uint4 bhr = *(const uint4*)(bhrow + sk);
    uint4 blr = *(const uint4*)(blrow + sk);

    for (int k0 = 0; k0 < K; k0 += 32) {
        float vv[8] = {a0r.x, a0r.y, a0r.z, a0r.w, a1r.x, a1r.y, a1r.z, a1r.w};
        unsigned hp[4], lp[4];
#pragma unroll
        for (int q = 0; q < 4; ++q) {
            unsigned short h0 = bf16_trunc(vv[q * 2]);
            unsigned short h1 = bf16_trunc(vv[q * 2 + 1]);
            unsigned short l0 = bf16_rne(vv[q * 2] - bf2f(h0));
            unsigned short l1 = bf16_rne(vv[q * 2 + 1] - bf2f(h1));
            hp[q] = (unsigned)h0 | ((unsigned)h1 << 16);
            lp[q] = (unsigned)l0 | ((unsigned)l1 << 16);
        }
        __syncthreads();
        *(uint4*)&Ah[sm][sk] = make_uint4(hp[0], hp[1], hp[2], hp[3]);
        *(uint4*)&Al[sm][sk] = make_uint4(lp[0], lp[1], lp[2], lp[3]);
        *(uint4*)&Bh[sm][sk] = bhr;
        *(uint4*)&Bl[sm][sk] = blr;
        const int kn = (k0 + 32 < K) ? k0 + 32 : 0;
        a0r = *(const float4*)(arow + kn + sk);
        a1r = *(const float4*)(arow + kn + sk + 4);
        bhr = *(const uint4*)(bhrow + kn + sk);
        blr = *(const uint4*)(blrow + kn + sk);
        __syncthreads();
        s16x8 ah = *(const s16x8*)&Ah[w * 16 + l15][lhi * 8];
        s16x8 al2 = *(const s16x8*)&Al[w * 16 + l15][lhi * 8];
        __builtin_amdgcn_s_setprio(1);
#pragma unroll
        for (int cf = 0; cf < 4; ++cf) {
            s16x8 bh = *(const s16x8*)&Bh[cf * 16 + l15][lhi * 8];
            s16x8 bl = *(const s16x8*)&Bl[cf * 16 + l15][lhi * 8];
            acc[cf] = __builtin_amdgcn_mfma_f32_16x16x32_bf16(ah, bh, acc[cf], 0, 0, 0);
            acc[cf] = __builtin_amdgcn_mfma_f32_16x16x32_bf16(ah, bl, acc[cf], 0, 0, 0);
            acc[cf] = __builtin_amdgcn_mfma_f32_16x16x32_bf16(al2, bh, acc[cf], 0, 0, 0);
        }
        __builtin_amdgcn_s_setprio(0);
    }

#pragma unroll
    for (int cf = 0; cf < 4; ++cf) {
        const int col = bn + cf * 16 + l15;
        float bv = BIAS ? bias[col] : 0.0f;
#pragma unroll
        for (int r = 0; r < 4; ++r) {
            const int row = bm + w * 16 + lhi * 4 + r;
            float v = acc[cf][r] + bv;
            if (EPI == 1) {
                C[(size_t)row * Nn + col] = v;
                o0[(size_t)col * NROWS + row] = bf16_rne(v);
            } else if (EPI == 2) {
                if (col < 256)      o0[(size_t)row * 256 + col] = bf16_rne(v);
                else if (col < 512) o1[(size_t)row * 256 + (col - 256)] = bf16_rne(v);
                else                o2[(size_t)(col - 512) * NROWS + row] = bf16_rne(v);
            } else {
                unsigned short hh = bf16_trunc(v);
                o0[(size_t)row * Nn + col] = hh;
                o1[(size_t)row * Nn + col] = bf16_rne(v - bf2f(hh));
            }
        }
    }
}

// ---------------------------------------------------------------------------
// p1 = Wh @ a[:256], p2 = Wh @ a[256:]
// ---------------------------------------------------------------------------
__global__ __launch_bounds__(256) void compute_p(
    const float* __restrict__ Wh, const float* __restrict__ a,
    float* __restrict__ p1, float* __restrict__ p2)
{
    const int row = blockIdx.x * 16 + (threadIdx.x >> 4);
    const int c = threadIdx.x & 15;
    float s1 = 0.f, s2 = 0.f;
    for (int f = c; f < 256; f += 16) {
        float w = Wh[(size_t)row * 256 + f];
        s1 += w * a[f];
        s2 += w * a[256 + f];
    }
    s1 = wsum16(s1);
    s2 = wsum16(s2);
    if (c == 0) { p1[row] = s1; p2[row] = s2; }
}

// ---------------------------------------------------------------------------
// Global max of p2 (single block).
// ---------------------------------------------------------------------------
__global__ __launch_bounds__(256) void p2max_kernel(
    const float* __restrict__ p2, float* __restrict__ p2m)
{
    __shared__ float red[4];
    const int tid = threadIdx.x;
    float v = -3.0e38f;
#pragma unroll
    for (int k = 0; k < 16; ++k) v = fmaxf(v, p2[tid + k * 256]);
#pragma unroll
    for (int o = 32; o; o >>= 1) v = fmaxf(v, __shfl_xor(v, o, 64));
    if ((tid & 63) == 0) red[tid >> 6] = v;
    __syncthreads();
    if (tid == 0) p2m[0] = fmaxf(fmaxf(red[0], red[1]), fmaxf(red[2], red[3]));
}

// ---------------------------------------------------------------------------
// norms1/norms2: Cauchy-Schwarz bound M[i][h] = ||q_i||*max||k||/16.
// ---------------------------------------------------------------------------
__global__ __launch_bounds__(256) void norms1(
    const unsigned short* __restrict__ qh, const unsigned short* __restrict__ kh,
    float* __restrict__ qn2, float* __restrict__ knp)
{
    __shared__ float kn[16][4];
    const int tid = threadIdx.x;
    const int r16 = tid >> 4;
    const int c = tid & 15;
    const int i = blockIdx.x * 16 + r16;
#pragma unroll
    for (int h = 0; h < 4; ++h) {
        float sq = 0.f, sk = 0.f;
#pragma unroll
        for (int d = 0; d < 4; ++d) {
            float qv = bf2f(qh[(size_t)i * 256 + h * 64 + c + d * 16]);
            float kv = bf2f(kh[(size_t)i * 256 + h * 64 + c + d * 16]);
            sq += qv * qv; sk += kv * kv;
        }
        sq = wsum16(sq); sk = wsum16(sk);
        if (c == 0) { qn2[i * 4 + h] = sq; kn[r16][h] = sk; }
    }
    __syncthreads();
    if (tid < 4) {
        float m = 0.f;
#pragma unroll
        for (int r = 0; r < 16; ++r) m = fmaxf(m, kn[r][tid]);
        knp[blockIdx.x * 4 + tid] = m;
    }
}

__global__ __launch_bounds__(256) void norms2(
    const float* __restrict__ qn2, const float* __restrict__ knp,
    float* __restrict__ Mb)
{
    __shared__ float red[4][4];
    __shared__ float kmax[4];
    const int tid = threadIdx.x;
    float v[4];
#pragma unroll
    for (int h = 0; h < 4; ++h) v[h] = knp[tid * 4 + h];
#pragma unroll
    for (int h = 0; h < 4; ++h)
#pragma unroll
        for (int o = 32; o; o >>= 1) v[h] = fmaxf(v[h], __shfl_xor(v[h], o, 64));
    if ((tid & 63) == 0) {
#pragma unroll
        for (int h = 0; h < 4; ++h) red[tid >> 6][h] = v[h];
    }
    __syncthreads();
    if (tid < 4)
        kmax[tid] = fmaxf(fmaxf(red[0][tid], red[1][tid]), fmaxf(red[2][tid], red[3][tid]));
    __syncthreads();
    const int i = blockIdx.x * 256 + tid;
#pragma unroll
    for (int h = 0; h < 4; ++h)
        Mb[i * 4 + h] = sqrtf(qn2[i * 4 + h] * kmax[h]) * SCALE;
}

// ---------------------------------------------------------------------------
// zsum (r7 structure, 8 chunks): z partials, fixed bound M, no in-loop
// barriers, K prefetched. grid = 8 chunks x 256 rowtiles. 4 waves = 4 heads,
// per-head MFMA sequence identical to pvds.
// ---------------------------------------------------------------------------
__global__ __launch_bounds__(256) void zsum_kernel(
    const unsigned short* __restrict__ qh_g, const unsigned short* __restrict__ kh_g,
    const float* __restrict__ Mb, float* __restrict__ zpart)
{
    const int tid = threadIdx.x;
    const int h = tid >> 6;
    const int ln = tid & 63;
    const int l15 = ln & 15;
    const int lhi = ln >> 4;
    const int rt = blockIdx.x & 255;
    const int ch = blockIdx.x >> 8;
    const int i0 = rt * 16;
    const int jb = ch * CHJ;

    s16x8 qA[2];
#pragma unroll
    for (int ks = 0; ks < 2; ++ks)
        qA[ks] = *(const s16x8*)(qh_g + (size_t)(i0 + l15) * 256 + h * 64 + ks * 32 + lhi * 8);
    float M[4];
#pragma unroll
    for (int r = 0; r < 4; ++r) M[r] = Mb[(i0 + lhi * 4 + r) * 4 + h];

    float z[4] = {0.f, 0.f, 0.f, 0.f};
    s16x8 kfc[2][2];
#pragma unroll
    for (int nt = 0; nt < 2; ++nt)
#pragma unroll
        for (int ks = 0; ks < 2; ++ks)
            kfc[nt][ks] = *(const s16x8*)(kh_g + (size_t)(jb + nt * 16 + l15) * 256 +
                                          h * 64 + ks * 32 + lhi * 8);

    for (int tt = 0; tt < 16; ++tt) {
        const int jn = jb + ((tt + 1) & 15) * 32;
        f32x4 acc[2] = {{0.f,0.f,0.f,0.f},{0.f,0.f,0.f,0.f}};
        __builtin_amdgcn_s_setprio(1);
#pragma unroll
        for (int ks = 0; ks < 2; ++ks)
#pragma unroll
            for (int nt = 0; nt < 2; ++nt)
                acc[nt] = __builtin_amdgcn_mfma_f32_16x16x32_bf16(qA[ks], kfc[nt][ks], acc[nt], 0, 0, 0);
        __builtin_amdgcn_s_setprio(0);
#pragma unroll
        for (int nt = 0; nt < 2; ++nt)
#pragma unroll
            for (int ks = 0; ks < 2; ++ks)
                kfc[nt][ks] = *(const s16x8*)(kh_g + (size_t)(jn + nt * 16 + l15) * 256 +
                                              h * 64 + ks * 32 + lhi * 8);
#pragma unroll
        for (int r = 0; r < 4; ++r)
            z[r] += __expf(fmaf(acc[0][r], SCALE, -M[r])) + __expf(fmaf(acc[1][r], SCALE, -M[r]));
    }
#pragma unroll
    for (int r = 0; r < 4; ++r) {
        float zz = wsum16(z[r]);
        if (l15 == 0)
            zpart[(((size_t)(i0 + lhi * 4 + r) * 4 + h) * NCHUNK) + ch] = zz;
    }
}

// ---------------------------------------------------------------------------
// pvds (r7 structure + full PV + 8 chunks + f32 atomic pacc):
// dots (normalized bf16) -> PV (full 64 dims/head) + dsum. 1 barrier/tile
// via double-buffered dots LDS. grid = 8 chunks x 256 rowtiles.
// ---------------------------------------------------------------------------
__global__ __launch_bounds__(256) void pvds_kernel(
    const unsigned short* __restrict__ qh_g, const unsigned short* __restrict__ kh_g,
    const unsigned short* __restrict__ vth_g,
    const float* __restrict__ Mb, const float* __restrict__ zpart,
    unsigned short* __restrict__ dsum_g, float* __restrict__ pacc_g)
{
    enum { D0 = 0, D1 = 5120, MIZ = 10240, SMEMSZ = 10752 };
    __shared__ __align__(16) char smem[SMEMSZ];

    const int tid = threadIdx.x;
    const int h = tid >> 6;
    const int ln = tid & 63;
    const int l15 = ln & 15;
    const int lhi = ln >> 4;
    const int rt = blockIdx.x & 255;
    const int ch = blockIdx.x >> 8;
    const int i0 = rt * 16;
    const int jb = ch * CHJ;
    const int srow = tid >> 4;
    const int sc2 = (tid & 15) * 2;

    if (tid < 64) {
        int hh = tid >> 4, row = tid & 15;
        const float* zb = zpart + ((size_t)(i0 + row) * 4 + hh) * NCHUNK;
        float z = 0.f;
#pragma unroll
        for (int c = 0; c < NCHUNK; ++c) z += zb[c];
        float* fl = (float*)(smem + MIZ);
        fl[(hh * 16 + row) * 2] = Mb[(i0 + row) * 4 + hh];
        fl[(hh * 16 + row) * 2 + 1] = 1.0f / z;
    }

    s16x8 qA[2];
#pragma unroll
    for (int ks = 0; ks < 2; ++ks)
        qA[ks] = *(const s16x8*)(qh_g + (size_t)(i0 + l15) * 256 + h * 64 + ks * 32 + lhi * 8);
    __syncthreads();

    float m_f[4], iz_f[4];
#pragma unroll
    for (int r = 0; r < 4; ++r) {
        m_f[r]  = ((const float*)(smem + MIZ))[(h * 16 + lhi * 4 + r) * 2];
        iz_f[r] = ((const float*)(smem + MIZ))[(h * 16 + lhi * 4 + r) * 2 + 1];
    }

    s16x8 kfc[2][2], vfc[4];
#pragma unroll
    for (int nt = 0; nt < 2; ++nt)
#pragma unroll
        for (int ks = 0; ks < 2; ++ks)
            kfc[nt][ks] = *(const s16x8*)(kh_g + (size_t)(jb + nt * 16 + l15) * 256 +
                                          h * 64 + ks * 32 + lhi * 8);
#pragma unroll
    for (int nt2 = 0; nt2 < 4; ++nt2)
        vfc[nt2] = *(const s16x8*)(vth_g + (size_t)(h * 64 + nt2 * 16 + l15) * 4096 +
                                   jb + lhi * 8);

    f32x4 pacc[4];
#pragma unroll
    for (int nt2 = 0; nt2 < 4; ++nt2) pacc[nt2] = (f32x4){0.f, 0.f, 0.f, 0.f};

    for (int tt = 0; tt < 16; ++tt) {
        const int j0 = jb + tt * 32;
        const int jn = jb + ((tt + 1) & 15) * 32;
        const int buf = (tt & 1) ? D1 : D0;

        // ---- QK (hi, sequence identical to zsum) ----
        f32x4 acc[2] = {{0.f,0.f,0.f,0.f},{0.f,0.f,0.f,0.f}};
        __builtin_amdgcn_s_setprio(1);
#pragma unroll
        for (int ks = 0; ks < 2; ++ks)
#pragma unroll
            for (int nt = 0; nt < 2; ++nt)
                acc[nt] = __builtin_amdgcn_mfma_f32_16x16x32_bf16(qA[ks], kfc[nt][ks], acc[nt], 0, 0, 0);
        __builtin_amdgcn_s_setprio(0);
        // prefetch K(t+1)
#pragma unroll
        for (int nt = 0; nt < 2; ++nt)
#pragma unroll
            for (int ks = 0; ks < 2; ++ks)
                kfc[nt][ks] = *(const s16x8*)(kh_g + (size_t)(jn + nt * 16 + l15) * 256 +
                                              h * 64 + ks * 32 + lhi * 8);
        // dots -> LDS (bf16)
#pragma unroll
        for (int nt = 0; nt < 2; ++nt)
#pragma unroll
            for (int r = 0; r < 4; ++r) {
                float d = __expf(fmaf(acc[nt][r], SCALE, -m_f[r])) * iz_f[r];
                int row = lhi * 4 + r;
                *(unsigned short*)(smem + buf + h * 1280 + row * 80 + (nt * 16 + l15) * 2) = bf16_rne(d);
            }
        __syncthreads();   // dots(t) visible (dbuf covers WAR)

        // ---- PV (full head: 4 x 16 dims) ----
        {
            s16x8 dA = *(const s16x8*)(smem + buf + h * 1280 + l15 * 80 + lhi * 16);
            __builtin_amdgcn_s_setprio(1);
#pragma unroll
            for (int nt2 = 0; nt2 < 4; ++nt2)
                pacc[nt2] = __builtin_amdgcn_mfma_f32_16x16x32_bf16(dA, vfc[nt2], pacc[nt2], 0, 0, 0);
            __builtin_amdgcn_s_setprio(0);
        }
#pragma unroll
        for (int nt2 = 0; nt2 < 4; ++nt2)
            vfc[nt2] = *(const s16x8*)(vth_g + (size_t)(h * 64 + nt2 * 16 + l15) * 4096 +
                                       jn + lhi * 8);

        // ---- dsum (2 cells/thread) -> global bf16 ----
        {
            float ds0 = 0.f, ds1 = 0.f;
#pragma unroll
            for (int hh = 0; hh < 4; ++hh) {
                unsigned u = *(const unsigned*)(smem + buf + hh * 1280 + srow * 80 + sc2 * 2);
                ds0 += bflo(u); ds1 += bfhi(u);
            }
            unsigned pk = (unsigned)bf16_rne(ds0) | ((unsigned)bf16_rne(ds1) << 16);
            *(unsigned*)(dsum_g + (size_t)(i0 + srow) * 4096 + j0 + sc2) = pk;
        }
    }

    // ---- accumulate PV partial into global f32 ----
#pragma unroll
    for (int nt2 = 0; nt2 < 4; ++nt2)
#pragma unroll
        for (int r = 0; r < 4; ++r)
            atomicAdd(&pacc_g[(size_t)(i0 + lhi * 4 + r) * 256 + h * 64 + nt2 * 16 + l15],
                      pacc[nt2][r]);
}

// ---------------------------------------------------------------------------
// outer (r8 register-ptil structure, 8 chunks, f32 atomic wacc/L):
// LDS-free, barrier-free. Lane owns (i = lane&15, j = lhi*8..+7) = the MFMA
// A-fragment. 4 waves = 4 feature slices. grid = 8 chunks x 256 rowtiles.
// ---------------------------------------------------------------------------
__global__ __launch_bounds__(256) void outer_kernel(
    const unsigned short* __restrict__ wht_g, const unsigned short* __restrict__ dsum_g,
    const float* __restrict__ p1g, const float* __restrict__ p2g,
    const float* __restrict__ p2m, const int* __restrict__ adj,
    float* __restrict__ wacc_g, float* __restrict__ Lp_g)
{
    const int tid = threadIdx.x;
    const int w = tid >> 6;
    const int ln = tid & 63;
    const int l15 = ln & 15;
    const int lhi = ln >> 4;
    const int rt = blockIdx.x & 255;
    const int ch = blockIdx.x >> 8;
    const int i0 = rt * 16;
    const int jb = ch * CHJ;
    const int i = i0 + l15;

    const float p1v = p1g[i];
    float Mfix;
    {
        float s = p1v + p2m[0];
        Mfix = (s > 0.f ? s : ALPHA_LR * s) + 4.0f;
    }

    const int* adjB = adj + (size_t)i * 4096 + lhi * 8;
    const unsigned short* dsB = dsum_g + (size_t)i * 4096 + lhi * 8;
    const float* p2B = p2g + lhi * 8;
    const unsigned short* whB = wht_g + lhi * 8;

    // prefetch tile 0
    int4 a0 = *(const int4*)(adjB + jb);
    int4 a1 = *(const int4*)(adjB + jb + 4);
    u16x8 ds = *(const u16x8*)(dsB + jb);
    float4 q0 = *(const float4*)(p2B + jb);
    float4 q1 = *(const float4*)(p2B + jb + 4);
    s16x8 wf[4];
#pragma unroll
    for (int nt = 0; nt < 4; ++nt)
        wf[nt] = *(const s16x8*)(whB + (size_t)(w * 64 + nt * 16 + l15) * 4096 + jb);

    f32x4 acc[4];
#pragma unroll
    for (int nt = 0; nt < 4; ++nt) acc[nt] = (f32x4){0.f, 0.f, 0.f, 0.f};
    float Lacc = 0.0f;

    for (int t = 0; t < 16; ++t) {
        const int jn = jb + ((t + 1) & 15) * 32;

        float pr[8];
        {
            int am[8] = {a0.x, a0.y, a0.z, a0.w, a1.x, a1.y, a1.z, a1.w};
            float pv[8] = {q0.x, q0.y, q0.z, q0.w, q1.x, q1.y, q1.z, q1.w};
#pragma unroll
            for (int k = 0; k < 8; ++k) {
                float e = p1v + pv[k];
                e = e > 0.f ? e : ALPHA_LR * e;
                float arg = e + bf2f((unsigned short)ds[k]) - Mfix;
                pr[k] = (am[k] > 0) ? __expf(arg) : 0.f;
                Lacc += pr[k];
            }
        }
        // prefetch scalars t+1
        a0 = *(const int4*)(adjB + jn);
        a1 = *(const int4*)(adjB + jn + 4);
        ds = *(const u16x8*)(dsB + jn);
        q0 = *(const float4*)(p2B + jn);
        q1 = *(const float4*)(p2B + jn + 4);

        // A fragment from registers
        s16x8 pA;
#pragma unroll
        for (int k = 0; k < 8; ++k) pA[k] = (short)bf16_rne(pr[k]);

        __builtin_amdgcn_s_setprio(1);
#pragma unroll
        for (int nt = 0; nt < 4; ++nt)
            acc[nt] = __builtin_amdgcn_mfma_f32_16x16x32_bf16(pA, wf[nt], acc[nt], 0, 0, 0);
        __builtin_amdgcn_s_setprio(0);

        // prefetch Wh frags t+1
#pragma unroll
        for (int nt = 0; nt < 4; ++nt)
            wf[nt] = *(const s16x8*)(whB + (size_t)(w * 64 + nt * 16 + l15) * 4096 + jn);
    }

    Lacc += __shfl_xor(Lacc, 16);
    Lacc += __shfl_xor(Lacc, 32);
    if (w == 0 && ln < 16) atomicAdd(&Lp_g[i], Lacc);

#pragma unroll
    for (int nt = 0; nt < 4; ++nt)
#pragma unroll
        for (int r = 0; r < 4; ++r)
            atomicAdd(&wacc_g[(size_t)(i0 + lhi * 4 + r) * 256 + w * 64 + nt * 16 + l15],
                      acc[nt][r]);
}

// ---------------------------------------------------------------------------
// Merge: read f32 accumulators, Wh0 row softmax, normalize, elu, store.
// ---------------------------------------------------------------------------
__global__ __launch_bounds__(256) void merge_kernel(
    const float* __restrict__ pacc_g, const float* __restrict__ wacc_g,
    const float* __restrict__ Lp, float* __restrict__ out)
{
    const int rt = blockIdx.x;
    const int tid = threadIdx.x;
    const int row = tid >> 4;
    const int cg = tid & 15;
    const int i = rt * 16 + row;

    const float invL = 1.0f / fmaxf(Lp[i], 1e-30f);

    float p[16], wv[16];
    const size_t b = (size_t)i * 256 + cg * 16;
#pragma unroll
    for (int k4 = 0; k4 < 4; ++k4) {
        float4 pv = *(const float4*)(pacc_g + b + k4 * 4);
        float4 wvv = *(const float4*)(wacc_g + b + k4 * 4);
        p[k4*4+0] = pv.x; p[k4*4+1] = pv.y; p[k4*4+2] = pv.z; p[k4*4+3] = pv.w;
        wv[k4*4+0] = wvv.x; wv[k4*4+1] = wvv.y; wv[k4*4+2] = wvv.z; wv[k4*4+3] = wvv.w;
    }

    float mx = -3.0e38f;
#pragma unroll
    for (int k = 0; k < 16; ++k) mx = fmaxf(mx, p[k]);
    mx = wmax16(mx);
    float sm = 0.f;
#pragma unroll
    for (int k = 0; k < 16; ++k) { p[k] = __expf(p[k] - mx); sm += p[k]; }
    sm = wsum16(sm);
    const float inv = 1.0f / sm;

    float* orow = out + (size_t)i * 256 + cg * 16;
#pragma unroll
    for (int k4 = 0; k4 < 4; ++k4) {
        float4 o;
        float v;
        v = wv[k4*4+0] * invL + p[k4*4+0] * inv; o.x = v > 0.f ? v : __expf(v) - 1.f;
        v = wv[k4*4+1] * invL + p[k4*4+1] * inv; o.y = v > 0.f ? v : __expf(v) - 1.f;
        v = wv[k4*4+2] * invL + p[k4*4+2] * inv; o.z = v > 0.f ? v : __expf(v) - 1.f;
        v = wv[k4*4+3] * invL + p[k4*4+3] * inv; o.w = v > 0.f ? v : __expf(v) - 1.f;
        *(float4*)(orow + k4 * 4) = o;
    }
}

extern "C" void kernel_launch(void* const* d_in, const int* in_sizes, int n_in,
                              void* d_out, int out_size, void* d_ws, size_t ws_size,
                              hipStream_t stream)
{
    const float* h      = (const float*)d_in[0];
    const int*   adj    = (const int*)d_in[1];
    const float* W      = (const float*)d_in[2];
    const float* Wl_w   = (const float*)d_in[3];
    const float* Wl_b   = (const float*)d_in[4];
    const float* Wqkv_w = (const float*)d_in[5];
    const float* Wqkv_b = (const float*)d_in[6];
    const float* a      = (const float*)d_in[7];
    float* out = (float*)d_out;

    char* wsb = (char*)d_ws;
    unsigned short* qh     = (unsigned short*)(wsb + 0);          // 2 MB
    unsigned short* kh     = (unsigned short*)(wsb + 2097152);    // 2 MB
    unsigned short* vth    = (unsigned short*)(wsb + 4194304);    // 2 MB
    unsigned short* wht    = (unsigned short*)(wsb + 6291456);    // 2 MB
    unsigned short* dsum_b = (unsigned short*)(wsb + 8388608);    // 32 MB
    float*          pacc_f = (float*)(wsb + 41943040);            // 4 MB
    float*          wacc_f = (float*)(wsb + 46137344);            // 4 MB
    float*          p1b    = (float*)(wsb + 50331648);
    float*          p2b    = (float*)(wsb + 50348032);
    float*          p2m    = (float*)(wsb + 50364416);
    float*          qn2    = (float*)(wsb + 50368512);            // 64 KB
    float*          knp    = (float*)(wsb + 50434048);            // 4 KB
    float*          Mb     = (float*)(wsb + 50438144);            // 64 KB
    float*          zpart  = (float*)(wsb + 50503680);            // 512 KB
    float*          Lp     = (float*)(wsb + 51027968);            // 16 KB
    // gemm-phase temporaries overlay the dsum region (dead before pvds)
    float*          Whb    = (float*)(wsb + 8388608);             // 4 MB
    unsigned short* Whi    = (unsigned short*)(wsb + 12582912);   // 256 KB
    unsigned short* Wlo    = Whi + 131072;
    unsigned short* Qhi    = Wlo + 131072;                        // 384 KB
    unsigned short* Qlo    = Qhi + 196608;
    unsigned short* WcThi  = Qlo + 196608;                        // 256 KB
    unsigned short* WcTlo  = WcThi + 131072;

    // zero the f32 accumulators
    hipMemsetAsync(pacc_f, 0, 4194304, stream);
    hipMemsetAsync(wacc_f, 0, 4194304, stream);
    hipMemsetAsync(Lp, 0, 16384, stream);

    dim3 blk(256);
    wprep<<<dim3(768), blk, 0, stream>>>(W, Wqkv_w, Whi, Wlo, Qhi, Qlo);
    gemm_mfma<3, false><<<dim3(8, 4), blk, 0, stream>>>(
        Wl_w, Whi, Wlo, nullptr, nullptr, WcThi, WcTlo, nullptr, 256, 512, 256);
    gemm_mfma<1, true><<<dim3(4, 64), blk, 0, stream>>>(
        h, WcThi, WcTlo, Wl_b, Whb, wht, nullptr, nullptr, 4096, 256, 512);
    gemm_mfma<2, true><<<dim3(12, 64), blk, 0, stream>>>(
        Whb, Qhi, Qlo, Wqkv_b, nullptr, qh, kh, vth, 4096, 768, 256);
    compute_p<<<dim3(256), blk, 0, stream>>>(Whb, a, p1b, p2b);
    p2max_kernel<<<dim3(1), blk, 0, stream>>>(p2b, p2m);
    norms1<<<dim3(256), blk, 0, stream>>>(qh, kh, qn2, knp);
    norms2<<<dim3(16), blk, 0, stream>>>(qn2, knp, Mb);
    zsum_kernel<<<dim3(2048), blk, 0, stream>>>(qh, kh, Mb, zpart);
    pvds_kernel<<<dim3(2048), blk, 0, stream>>>(qh, kh, vth, Mb, zpart, dsum_b, pacc_f);
    outer_kernel<<<dim3(2048), blk, 0, stream>>>(wht, dsum_b, p1b, p2b, p2m, adj, wacc_f, Lp);
    merge_kernel<<<dim3(256), blk, 0, stream>>>(pacc_f, wacc_f, Lp, out);
}

// Round 10
// 373.382 us; speedup vs baseline: 1.0100x; 1.0100x over previous
//
#include <hip/hip_runtime.h>

typedef float  f32x4 __attribute__((ext_vector_type(4)));
typedef short  s16x8 __attribute__((ext_vector_type(8)));
typedef unsigned short u16x8 __attribute__((ext_vector_type(8)));

#define NROWS 4096
#define ALPHA_LR 0.2f
#define SCALE 0.0625f
#define NCHUNK 4
#define CHJ 1024

static __device__ __forceinline__ unsigned short bf16_rne(float x) {
    unsigned u = __float_as_uint(x);
    u += 0x7fffu + ((u >> 16) & 1u);
    return (unsigned short)(u >> 16);
}
static __device__ __forceinline__ unsigned short bf16_trunc(float x) {
    return (unsigned short)(__float_as_uint(x) >> 16);
}
static __device__ __forceinline__ float bf2f(unsigned short h) {
    return __uint_as_float(((unsigned)h) << 16);
}
static __device__ __forceinline__ float bflo(unsigned u) { return __uint_as_float(u << 16); }
static __device__ __forceinline__ float bfhi(unsigned u) { return __uint_as_float(u & 0xffff0000u); }
static __device__ __forceinline__ float wmax16(float v) {
#pragma unroll
    for (int o = 8; o; o >>= 1) v = fmaxf(v, __shfl_xor(v, o, 16));
    return v;
}
static __device__ __forceinline__ float wsum16(float v) {
#pragma unroll
    for (int o = 8; o; o >>= 1) v += __shfl_xor(v, o, 16);
    return v;
}

// ---------------------------------------------------------------------------
// Split all fp32 A-side matrices to bf16 hi/lo once (grid-stride).
// ---------------------------------------------------------------------------
__global__ __launch_bounds__(256) void wprep(
    const float* __restrict__ W, const float* __restrict__ Wq,
    const float* __restrict__ Wl, const float* __restrict__ hsrc,
    unsigned short* __restrict__ Whi, unsigned short* __restrict__ Wlo,
    unsigned short* __restrict__ Qhi, unsigned short* __restrict__ Qlo,
    unsigned short* __restrict__ WLhi, unsigned short* __restrict__ WLlo,
    unsigned short* __restrict__ Hhi, unsigned short* __restrict__ Hlo)
{
    for (int i = blockIdx.x * 256 + threadIdx.x; i < 2097152; i += gridDim.x * 256) {
        if (i < 131072) {
            float v = W[i];
            unsigned short hh = bf16_trunc(v);
            Whi[i] = hh; Wlo[i] = bf16_rne(v - bf2f(hh));
        }
        if (i < 196608) {
            float v = Wq[i];
            unsigned short hh = bf16_trunc(v);
            Qhi[i] = hh; Qlo[i] = bf16_rne(v - bf2f(hh));
        }
        if (i < 65536) {
            float v = Wl[i];
            unsigned short hh = bf16_trunc(v);
            WLhi[i] = hh; WLlo[i] = bf16_rne(v - bf2f(hh));
        }
        {
            float v = hsrc[i];
            unsigned short hh = bf16_trunc(v);
            Hhi[i] = hh; Hlo[i] = bf16_rne(v - bf2f(hh));
        }
    }
}

// ---------------------------------------------------------------------------
// MFMA GEMM, 3-term bf16 hi/lo split, A pre-split.
// EPI 1: o0/o1 = Whb hi/lo [row][col]; o2 = WhT bf16 [col*4096+row]
// EPI 2: col<256 -> o0 (q); col<512 -> o1 (k); else o2 = vT
// EPI 3: o0/o1 = hi/lo at [row*Nn+col] (WcT)
// ---------------------------------------------------------------------------
template <int EPI, bool BIAS>
__global__ __launch_bounds__(256) void gemm_mfma(
    const unsigned short* __restrict__ Ahi, const unsigned short* __restrict__ Alo,
    const unsigned short* __restrict__ Bhi, const unsigned short* __restrict__ Blo,
    const float* __restrict__ bias,
    unsigned short* __restrict__ o0, unsigned short* __restrict__ o1,
    unsigned short* __restrict__ o2,
    int M, int Nn, int K)
{
    __shared__ unsigned short Ah[64][40];
    __shared__ unsigned short Al[64][40];
    __shared__ unsigned short Bh[64][40];
    __shared__ unsigned short Bl[64][40];

    const int tid = threadIdx.x;
    const int w = tid >> 6;
    const int ln = tid & 63;
    const int l15 = ln & 15;
    const int lhi = ln >> 4;
    const int bm = blockIdx.y * 64;
    const int bn = blockIdx.x * 64;
    const int sm = tid >> 2;
    const int sk = (tid & 3) * 8;

    f32x4 acc[4];
#pragma unroll
    for (int cf = 0; cf < 4; ++cf) acc[cf] = (f32x4){0.f, 0.f, 0.f, 0.f};

    const unsigned short* ahrow = &Ahi[(size_t)(bm + sm) * K];
    const unsigned short* alrow = &Alo[(size_t)(bm + sm) * K];
    const unsigned short* bhrow = &Bhi[(size_t)(bn + sm) * K];
    const unsigned short* blrow = &Blo[(size_t)(bn + sm) * K];

    uint4 ahr = *(const uint4*)(ahrow + sk);
    uint4 alr = *(const uint4*)(alrow + sk);
    uint4 bhr = *(const uint4*)(bhrow + sk);
    uint4 blr = *(const uint4*)(blrow + sk);

    for (int k0 = 0; k0 < K; k0 += 32) {
        __syncthreads();
        *(uint4*)&Ah[sm][sk] = ahr;
        *(uint4*)&Al[sm][sk] = alr;
        *(uint4*)&Bh[sm][sk] = bhr;
        *(uint4*)&Bl[sm][sk] = blr;
        const int kn = (k0 + 32 < K) ? k0 + 32 : 0;
        ahr = *(const uint4*)(ahrow + kn + sk);
        alr = *(const uint4*)(alrow + kn + sk);
        bhr = *(const uint4*)(bhrow + kn + sk);
        blr = *(const uint4*)(blrow + kn + sk);
        __syncthreads();
        s16x8 ah = *(const s16x8*)&Ah[w * 16 + l15][lhi * 8];
        s16x8 al2 = *(const s16x8*)&Al[w * 16 + l15][lhi * 8];
        __builtin_amdgcn_s_setprio(1);
#pragma unroll
        for (int cf = 0; cf < 4; ++cf) {
            s16x8 bh = *(const s16x8*)&Bh[cf * 16 + l15][lhi * 8];
            s16x8 bl = *(const s16x8*)&Bl[cf * 16 + l15][lhi * 8];
            acc[cf] = __builtin_amdgcn_mfma_f32_16x16x32_bf16(ah, bh, acc[cf], 0, 0, 0);
            acc[cf] = __builtin_amdgcn_mfma_f32_16x16x32_bf16(ah, bl, acc[cf], 0, 0, 0);
            acc[cf] = __builtin_amdgcn_mfma_f32_16x16x32_bf16(al2, bh, acc[cf], 0, 0, 0);
        }
        __builtin_amdgcn_s_setprio(0);
    }

#pragma unroll
    for (int cf = 0; cf < 4; ++cf) {
        const int col = bn + cf * 16 + l15;
        float bv = BIAS ? bias[col] : 0.0f;
#pragma unroll
        for (int r = 0; r < 4; ++r) {
            const int row = bm + w * 16 + lhi * 4 + r;
            float v = acc[cf][r] + bv;
            if (EPI == 1) {
                unsigned short hh = bf16_trunc(v);
                o0[(size_t)row * Nn + col] = hh;
                o1[(size_t)row * Nn + col] = bf16_rne(v - bf2f(hh));
                o2[(size_t)col * NROWS + row] = bf16_rne(v);
            } else if (EPI == 2) {
                if (col < 256)      o0[(size_t)row * 256 + col] = bf16_rne(v);
                else if (col < 512) o1[(size_t)row * 256 + (col - 256)] = bf16_rne(v);
                else                o2[(size_t)(col - 512) * NROWS + row] = bf16_rne(v);
            } else {
                unsigned short hh = bf16_trunc(v);
                o0[(size_t)row * Nn + col] = hh;
                o1[(size_t)row * Nn + col] = bf16_rne(v - bf2f(hh));
            }
        }
    }
}

// ---------------------------------------------------------------------------
// p1 = Wh @ a[:256], p2 = Wh @ a[256:]   (Wh reconstructed from hi/lo)
// ---------------------------------------------------------------------------
__global__ __launch_bounds__(256) void compute_p(
    const unsigned short* __restrict__ WhbHi, const unsigned short* __restrict__ WhbLo,
    const float* __restrict__ a, float* __restrict__ p1, float* __restrict__ p2)
{
    const int row = blockIdx.x * 16 + (threadIdx.x >> 4);
    const int c = threadIdx.x & 15;
    float s1 = 0.f, s2 = 0.f;
    for (int f = c; f < 256; f += 16) {
        size_t idx = (size_t)row * 256 + f;
        float w = bf2f(WhbHi[idx]) + bf2f(WhbLo[idx]);
        s1 += w * a[f];
        s2 += w * a[256 + f];
    }
    s1 = wsum16(s1);
    s2 = wsum16(s2);
    if (c == 0) { p1[row] = s1; p2[row] = s2; }
}

// ---------------------------------------------------------------------------
// Global max of p2 (single block).
// ---------------------------------------------------------------------------
__global__ __launch_bounds__(256) void p2max_kernel(
    const float* __restrict__ p2, float* __restrict__ p2m)
{
    __shared__ float red[4];
    const int tid = threadIdx.x;
    float v = -3.0e38f;
#pragma unroll
    for (int k = 0; k < 16; ++k) v = fmaxf(v, p2[tid + k * 256]);
#pragma unroll
    for (int o = 32; o; o >>= 1) v = fmaxf(v, __shfl_xor(v, o, 64));
    if ((tid & 63) == 0) red[tid >> 6] = v;
    __syncthreads();
    if (tid == 0) p2m[0] = fmaxf(fmaxf(red[0], red[1]), fmaxf(red[2], red[3]));
}

// ---------------------------------------------------------------------------
// norms1/norms2: Cauchy-Schwarz bound M[i][h] = ||q_i||*max||k||/16.
// ---------------------------------------------------------------------------
__global__ __launch_bounds__(256) void norms1(
    const unsigned short* __restrict__ qh, const unsigned short* __restrict__ kh,
    float* __restrict__ qn2, float* __restrict__ knp)
{
    __shared__ float kn[16][4];
    const int tid = threadIdx.x;
    const int r16 = tid >> 4;
    const int c = tid & 15;
    const int i = blockIdx.x * 16 + r16;
#pragma unroll
    for (int h = 0; h < 4; ++h) {
        float sq = 0.f, sk = 0.f;
#pragma unroll
        for (int d = 0; d < 4; ++d) {
            float qv = bf2f(qh[(size_t)i * 256 + h * 64 + c + d * 16]);
            float kv = bf2f(kh[(size_t)i * 256 + h * 64 + c + d * 16]);
            sq += qv * qv; sk += kv * kv;
        }
        sq = wsum16(sq); sk = wsum16(sk);
        if (c == 0) { qn2[i * 4 + h] = sq; kn[r16][h] = sk; }
    }
    __syncthreads();
    if (tid < 4) {
        float m = 0.f;
#pragma unroll
        for (int r = 0; r < 16; ++r) m = fmaxf(m, kn[r][tid]);
        knp[blockIdx.x * 4 + tid] = m;
    }
}

__global__ __launch_bounds__(256) void norms2(
    const float* __restrict__ qn2, const float* __restrict__ knp,
    float* __restrict__ Mb)
{
    __shared__ float red[4][4];
    __shared__ float kmax[4];
    const int tid = threadIdx.x;
    float v[4];
#pragma unroll
    for (int h = 0; h < 4; ++h) v[h] = knp[tid * 4 + h];
#pragma unroll
    for (int h = 0; h < 4; ++h)
#pragma unroll
        for (int o = 32; o; o >>= 1) v[h] = fmaxf(v[h], __shfl_xor(v[h], o, 64));
    if ((tid & 63) == 0) {
#pragma unroll
        for (int h = 0; h < 4; ++h) red[tid >> 6][h] = v[h];
    }
    __syncthreads();
    if (tid < 4)
        kmax[tid] = fmaxf(fmaxf(red[0][tid], red[1][tid]), fmaxf(red[2][tid], red[3][tid]));
    __syncthreads();
    const int i = blockIdx.x * 256 + tid;
#pragma unroll
    for (int h = 0; h < 4; ++h)
        Mb[i * 4 + h] = sqrtf(qn2[i * 4 + h] * kmax[h]) * SCALE;
}

// ---------------------------------------------------------------------------
// zsum: pair-pipelined (2 tiles/iter = 4 independent MFMA chains), fixed
// bound M, no in-loop barriers. grid = 4 chunks x 256 rowtiles.
// Per-tile MFMA/exp sequence identical to pvds.
// ---------------------------------------------------------------------------
__global__ __launch_bounds__(256) void zsum_kernel(
    const unsigned short* __restrict__ qh_g, const unsigned short* __restrict__ kh_g,
    const float* __restrict__ Mb, float* __restrict__ zpart)
{
    const int tid = threadIdx.x;
    const int h = tid >> 6;
    const int ln = tid & 63;
    const int l15 = ln & 15;
    const int lhi = ln >> 4;
    const int rt = blockIdx.x & 255;
    const int ch = blockIdx.x >> 8;
    const int i0 = rt * 16;
    const int jb = ch * CHJ;

    s16x8 qA[2];
#pragma unroll
    for (int ks = 0; ks < 2; ++ks)
        qA[ks] = *(const s16x8*)(qh_g + (size_t)(i0 + l15) * 256 + h * 64 + ks * 32 + lhi * 8);
    float M[4];
#pragma unroll
    for (int r = 0; r < 4; ++r) M[r] = Mb[(i0 + lhi * 4 + r) * 4 + h];

    const unsigned short* kBase = kh_g + (size_t)l15 * 256 + h * 64 + lhi * 8;

    float z[4] = {0.f, 0.f, 0.f, 0.f};
    s16x8 kf[2][2][2];
#pragma unroll
    for (int t = 0; t < 2; ++t)
#pragma unroll
        for (int nt = 0; nt < 2; ++nt)
#pragma unroll
            for (int ks = 0; ks < 2; ++ks)
                kf[t][nt][ks] = *(const s16x8*)(kBase + (size_t)(jb + t * 32 + nt * 16) * 256 + ks * 32);

    for (int pp = 0; pp < 16; ++pp) {
        const int jn = jb + ((pp + 1) & 15) * 64;
        f32x4 acc[2][2];
#pragma unroll
        for (int t = 0; t < 2; ++t)
#pragma unroll
            for (int nt = 0; nt < 2; ++nt) acc[t][nt] = (f32x4){0.f, 0.f, 0.f, 0.f};
        __builtin_amdgcn_s_setprio(1);
#pragma unroll
        for (int t = 0; t < 2; ++t)
#pragma unroll
            for (int nt = 0; nt < 2; ++nt) {
                acc[t][nt] = __builtin_amdgcn_mfma_f32_16x16x32_bf16(qA[0], kf[t][nt][0], acc[t][nt], 0, 0, 0);
                acc[t][nt] = __builtin_amdgcn_mfma_f32_16x16x32_bf16(qA[1], kf[t][nt][1], acc[t][nt], 0, 0, 0);
            }
        __builtin_amdgcn_s_setprio(0);
#pragma unroll
        for (int t = 0; t < 2; ++t)
#pragma unroll
            for (int nt = 0; nt < 2; ++nt)
#pragma unroll
                for (int ks = 0; ks < 2; ++ks)
                    kf[t][nt][ks] = *(const s16x8*)(kBase + (size_t)(jn + t * 32 + nt * 16) * 256 + ks * 32);
#pragma unroll
        for (int t = 0; t < 2; ++t)
#pragma unroll
            for (int nt = 0; nt < 2; ++nt)
#pragma unroll
                for (int r = 0; r < 4; ++r)
                    z[r] += __expf(fmaf(acc[t][nt][r], SCALE, -M[r]));
    }
#pragma unroll
    for (int r = 0; r < 4; ++r) {
        float zz = wsum16(z[r]);
        if (l15 == 0)
            zpart[(((size_t)(i0 + lhi * 4 + r) * 4 + h) * NCHUNK) + ch] = zz;
    }
}

// ---------------------------------------------------------------------------
// pvds: pair-pipelined, 1 barrier per 64 j (pair), pair-level double-buffered
// dots LDS. Full PV (64 dims/head). f32 atomic pacc. grid = 4 x 256.
// ---------------------------------------------------------------------------
__global__ __launch_bounds__(256) void pvds_kernel(
    const unsigned short* __restrict__ qh_g, const unsigned short* __restrict__ kh_g,
    const unsigned short* __restrict__ vth_g,
    const float* __restrict__ Mb, const float* __restrict__ zpart,
    unsigned short* __restrict__ dsum_g, float* __restrict__ pacc_g)
{
    enum { PB0 = 0, PB1 = 10240, MIZ = 20480, SMEMSZ = 20992 };
    __shared__ __align__(16) char smem[SMEMSZ];

    const int tid = threadIdx.x;
    const int h = tid >> 6;
    const int ln = tid & 63;
    const int l15 = ln & 15;
    const int lhi = ln >> 4;
    const int rt = blockIdx.x & 255;
    const int ch = blockIdx.x >> 8;
    const int i0 = rt * 16;
    const int jb = ch * CHJ;
    const int srow = tid >> 4;
    const int sc2 = (tid & 15) * 2;

    if (tid < 64) {
        int hh = tid >> 4, row = tid & 15;
        const float* zb = zpart + ((size_t)(i0 + row) * 4 + hh) * NCHUNK;
        float z = ((zb[0] + zb[1]) + zb[2]) + zb[3];
        float* fl = (float*)(smem + MIZ);
        fl[(hh * 16 + row) * 2] = Mb[(i0 + row) * 4 + hh];
        fl[(hh * 16 + row) * 2 + 1] = 1.0f / z;
    }

    s16x8 qA[2];
#pragma unroll
    for (int ks = 0; ks < 2; ++ks)
        qA[ks] = *(const s16x8*)(qh_g + (size_t)(i0 + l15) * 256 + h * 64 + ks * 32 + lhi * 8);
    __syncthreads();

    float m_f[4], iz_f[4];
#pragma unroll
    for (int r = 0; r < 4; ++r) {
        m_f[r]  = ((const float*)(smem + MIZ))[(h * 16 + lhi * 4 + r) * 2];
        iz_f[r] = ((const float*)(smem + MIZ))[(h * 16 + lhi * 4 + r) * 2 + 1];
    }

    const unsigned short* kBase = kh_g + (size_t)l15 * 256 + h * 64 + lhi * 8;
    const unsigned short* vBase = vth_g + (size_t)(h * 64 + l15) * 4096 + lhi * 8;

    s16x8 kf[2][2][2], vf[2][4];
#pragma unroll
    for (int t = 0; t < 2; ++t) {
#pragma unroll
        for (int nt = 0; nt < 2; ++nt)
#pragma unroll
            for (int ks = 0; ks < 2; ++ks)
                kf[t][nt][ks] = *(const s16x8*)(kBase + (size_t)(jb + t * 32 + nt * 16) * 256 + ks * 32);
#pragma unroll
        for (int nt2 = 0; nt2 < 4; ++nt2)
            vf[t][nt2] = *(const s16x8*)(vBase + (size_t)(nt2 * 16) * 4096 + jb + t * 32);
    }

    f32x4 pacc[4];
#pragma unroll
    for (int nt2 = 0; nt2 < 4; ++nt2) pacc[nt2] = (f32x4){0.f, 0.f, 0.f, 0.f};

    for (int pp = 0; pp < 16; ++pp) {
        const int j0 = jb + pp * 64;
        const int jn = jb + ((pp + 1) & 15) * 64;
        char* buf = smem + ((pp & 1) ? PB1 : PB0);

        // ---- QK both tiles (4 independent 2-chains) ----
        f32x4 acc[2][2];
#pragma unroll
        for (int t = 0; t < 2; ++t)
#pragma unroll
            for (int nt = 0; nt < 2; ++nt) acc[t][nt] = (f32x4){0.f, 0.f, 0.f, 0.f};
        __builtin_amdgcn_s_setprio(1);
#pragma unroll
        for (int t = 0; t < 2; ++t)
#pragma unroll
            for (int nt = 0; nt < 2; ++nt) {
                acc[t][nt] = __builtin_amdgcn_mfma_f32_16x16x32_bf16(qA[0], kf[t][nt][0], acc[t][nt], 0, 0, 0);
                acc[t][nt] = __builtin_amdgcn_mfma_f32_16x16x32_bf16(qA[1], kf[t][nt][1], acc[t][nt], 0, 0, 0);
            }
        __builtin_amdgcn_s_setprio(0);
        // reload K <- next pair
#pragma unroll
        for (int t = 0; t < 2; ++t)
#pragma unroll
            for (int nt = 0; nt < 2; ++nt)
#pragma unroll
                for (int ks = 0; ks < 2; ++ks)
                    kf[t][nt][ks] = *(const s16x8*)(kBase + (size_t)(jn + t * 32 + nt * 16) * 256 + ks * 32);
        // dots -> LDS (bf16, normalized)
#pragma unroll
        for (int t = 0; t < 2; ++t)
#pragma unroll
            for (int nt = 0; nt < 2; ++nt)
#pragma unroll
                for (int r = 0; r < 4; ++r) {
                    float d = __expf(fmaf(acc[t][nt][r], SCALE, -m_f[r])) * iz_f[r];
                    int row = lhi * 4 + r;
                    *(unsigned short*)(buf + t * 5120 + h * 1280 + row * 80 + (nt * 16 + l15) * 2) = bf16_rne(d);
                }
        __syncthreads();   // pair's dots visible (pair-dbuf covers WAR)

        // ---- PV both tiles ----
        __builtin_amdgcn_s_setprio(1);
#pragma unroll
        for (int t = 0; t < 2; ++t) {
            s16x8 dA = *(const s16x8*)(buf + t * 5120 + h * 1280 + l15 * 80 + lhi * 16);
#pragma unroll
            for (int nt2 = 0; nt2 < 4; ++nt2)
                pacc[nt2] = __builtin_amdgcn_mfma_f32_16x16x32_bf16(dA, vf[t][nt2], pacc[nt2], 0, 0, 0);
        }
        __builtin_amdgcn_s_setprio(0);
        // reload V <- next pair
#pragma unroll
        for (int t = 0; t < 2; ++t)
#pragma unroll
            for (int nt2 = 0; nt2 < 4; ++nt2)
                vf[t][nt2] = *(const s16x8*)(vBase + (size_t)(nt2 * 16) * 4096 + jn + t * 32);

        // ---- dsum both tiles -> global bf16 ----
#pragma unroll
        for (int t = 0; t < 2; ++t) {
            float ds0 = 0.f, ds1 = 0.f;
#pragma unroll
            for (int hh = 0; hh < 4; ++hh) {
                unsigned u = *(const unsigned*)(buf + t * 5120 + hh * 1280 + srow * 80 + sc2 * 2);
                ds0 += bflo(u); ds1 += bfhi(u);
            }
            unsigned pk = (unsigned)bf16_rne(ds0) | ((unsigned)bf16_rne(ds1) << 16);
            *(unsigned*)(dsum_g + (size_t)(i0 + srow) * 4096 + j0 + t * 32 + sc2) = pk;
        }
    }

#pragma unroll
    for (int nt2 = 0; nt2 < 4; ++nt2)
#pragma unroll
        for (int r = 0; r < 4; ++r)
            atomicAdd(&pacc_g[(size_t)(i0 + lhi * 4 + r) * 256 + h * 64 + nt2 * 16 + l15],
                      pacc[nt2][r]);
}

// ---------------------------------------------------------------------------
// outer: LDS-free, barrier-free, register ptil = MFMA A-fragment.
// grid = 4 chunks x 256 rowtiles, 32 tiles of 32 j.
// ---------------------------------------------------------------------------
__global__ __launch_bounds__(256) void outer_kernel(
    const unsigned short* __restrict__ wht_g, const unsigned short* __restrict__ dsum_g,
    const float* __restrict__ p1g, const float* __restrict__ p2g,
    const float* __restrict__ p2m, const int* __restrict__ adj,
    float* __restrict__ wacc_g, float* __restrict__ Lp_g)
{
    const int tid = threadIdx.x;
    const int w = tid >> 6;
    const int ln = tid & 63;
    const int l15 = ln & 15;
    const int lhi = ln >> 4;
    const int rt = blockIdx.x & 255;
    const int ch = blockIdx.x >> 8;
    const int i0 = rt * 16;
    const int jb = ch * CHJ;
    const int i = i0 + l15;

    const float p1v = p1g[i];
    float Mfix;
    {
        float s = p1v + p2m[0];
        Mfix = (s > 0.f ? s : ALPHA_LR * s) + 4.0f;
    }

    const int* adjB = adj + (size_t)i * 4096 + lhi * 8;
    const unsigned short* dsB = dsum_g + (size_t)i * 4096 + lhi * 8;
    const float* p2B = p2g + lhi * 8;
    const unsigned short* whB = wht_g + lhi * 8;

    int4 a0 = *(const int4*)(adjB + jb);
    int4 a1 = *(const int4*)(adjB + jb + 4);
    u16x8 ds = *(const u16x8*)(dsB + jb);
    float4 q0 = *(const float4*)(p2B + jb);
    float4 q1 = *(const float4*)(p2B + jb + 4);
    s16x8 wf[4];
#pragma unroll
    for (int nt = 0; nt < 4; ++nt)
        wf[nt] = *(const s16x8*)(whB + (size_t)(w * 64 + nt * 16 + l15) * 4096 + jb);

    f32x4 acc[4];
#pragma unroll
    for (int nt = 0; nt < 4; ++nt) acc[nt] = (f32x4){0.f, 0.f, 0.f, 0.f};
    float Lacc = 0.0f;

    for (int t = 0; t < 32; ++t) {
        const int jn = jb + ((t + 1) & 31) * 32;

        float pr[8];
        {
            int am[8] = {a0.x, a0.y, a0.z, a0.w, a1.x, a1.y, a1.z, a1.w};
            float pv[8] = {q0.x, q0.y, q0.z, q0.w, q1.x, q1.y, q1.z, q1.w};
#pragma unroll
            for (int k = 0; k < 8; ++k) {
                float e = p1v + pv[k];
                e = e > 0.f ? e : ALPHA_LR * e;
                float arg = e + bf2f((unsigned short)ds[k]) - Mfix;
                pr[k] = (am[k] > 0) ? __expf(arg) : 0.f;
                Lacc += pr[k];
            }
        }
        a0 = *(const int4*)(adjB + jn);
        a1 = *(const int4*)(adjB + jn + 4);
        ds = *(const u16x8*)(dsB + jn);
        q0 = *(const float4*)(p2B + jn);
        q1 = *(const float4*)(p2B + jn + 4);

        s16x8 pA;
#pragma unroll
        for (int k = 0; k < 8; ++k) pA[k] = (short)bf16_rne(pr[k]);

        __builtin_amdgcn_s_setprio(1);
#pragma unroll
        for (int nt = 0; nt < 4; ++nt)
            acc[nt] = __builtin_amdgcn_mfma_f32_16x16x32_bf16(pA, wf[nt], acc[nt], 0, 0, 0);
        __builtin_amdgcn_s_setprio(0);

#pragma unroll
        for (int nt = 0; nt < 4; ++nt)
            wf[nt] = *(const s16x8*)(whB + (size_t)(w * 64 + nt * 16 + l15) * 4096 + jn);
    }

    Lacc += __shfl_xor(Lacc, 16);
    Lacc += __shfl_xor(Lacc, 32);
    if (w == 0 && ln < 16) atomicAdd(&Lp_g[i], Lacc);

#pragma unroll
    for (int nt = 0; nt < 4; ++nt)
#pragma unroll
        for (int r = 0; r < 4; ++r)
            atomicAdd(&wacc_g[(size_t)(i0 + lhi * 4 + r) * 256 + w * 64 + nt * 16 + l15],
                      acc[nt][r]);
}

// ---------------------------------------------------------------------------
// Merge: read f32 accumulators, Wh0 row softmax, normalize, elu, store.
// ---------------------------------------------------------------------------
__global__ __launch_bounds__(256) void merge_kernel(
    const float* __restrict__ pacc_g, const float* __restrict__ wacc_g,
    const float* __restrict__ Lp, float* __restrict__ out)
{
    const int rt = blockIdx.x;
    const int tid = threadIdx.x;
    const int row = tid >> 4;
    const int cg = tid & 15;
    const int i = rt * 16 + row;

    const float invL = 1.0f / fmaxf(Lp[i], 1e-30f);

    float p[16], wv[16];
    const size_t b = (size_t)i * 256 + cg * 16;
#pragma unroll
    for (int k4 = 0; k4 < 4; ++k4) {
        float4 pv = *(const float4*)(pacc_g + b + k4 * 4);
        float4 wvv = *(const float4*)(wacc_g + b + k4 * 4);
        p[k4*4+0] = pv.x; p[k4*4+1] = pv.y; p[k4*4+2] = pv.z; p[k4*4+3] = pv.w;
        wv[k4*4+0] = wvv.x; wv[k4*4+1] = wvv.y; wv[k4*4+2] = wvv.z; wv[k4*4+3] = wvv.w;
    }

    float mx = -3.0e38f;
#pragma unroll
    for (int k = 0; k < 16; ++k) mx = fmaxf(mx, p[k]);
    mx = wmax16(mx);
    float sm = 0.f;
#pragma unroll
    for (int k = 0; k < 16; ++k) { p[k] = __expf(p[k] - mx); sm += p[k]; }
    sm = wsum16(sm);
    const float inv = 1.0f / sm;

    float* orow = out + (size_t)i * 256 + cg * 16;
#pragma unroll
    for (int k4 = 0; k4 < 4; ++k4) {
        float4 o;
        float v;
        v = wv[k4*4+0] * invL + p[k4*4+0] * inv; o.x = v > 0.f ? v : __expf(v) - 1.f;
        v = wv[k4*4+1] * invL + p[k4*4+1] * inv; o.y = v > 0.f ? v : __expf(v) - 1.f;
        v = wv[k4*4+2] * invL + p[k4*4+2] * inv; o.z = v > 0.f ? v : __expf(v) - 1.f;
        v = wv[k4*4+3] * invL + p[k4*4+3] * inv; o.w = v > 0.f ? v : __expf(v) - 1.f;
        *(float4*)(orow + k4 * 4) = o;
    }
}

extern "C" void kernel_launch(void* const* d_in, const int* in_sizes, int n_in,
                              void* d_out, int out_size, void* d_ws, size_t ws_size,
                              hipStream_t stream)
{
    const float* h      = (const float*)d_in[0];
    const int*   adj    = (const int*)d_in[1];
    const float* W      = (const float*)d_in[2];
    const float* Wl_w   = (const float*)d_in[3];
    const float* Wl_b   = (const float*)d_in[4];
    const float* Wqkv_w = (const float*)d_in[5];
    const float* Wqkv_b = (const float*)d_in[6];
    const float* a      = (const float*)d_in[7];
    float* out = (float*)d_out;

    char* wsb = (char*)d_ws;
    unsigned short* qh     = (unsigned short*)(wsb + 0);          // 2 MB
    unsigned short* kh     = (unsigned short*)(wsb + 2097152);    // 2 MB
    unsigned short* vth    = (unsigned short*)(wsb + 4194304);    // 2 MB
    unsigned short* wht    = (unsigned short*)(wsb + 6291456);    // 2 MB
    unsigned short* dsum_b = (unsigned short*)(wsb + 8388608);    // 32 MB
    float*          pacc_f = (float*)(wsb + 41943040);            // 4 MB
    float*          wacc_f = (float*)(wsb + 46137344);            // 4 MB
    float*          p1b    = (float*)(wsb + 50331648);
    float*          p2b    = (float*)(wsb + 50348032);
    float*          p2m    = (float*)(wsb + 50364416);
    float*          qn2    = (float*)(wsb + 50368512);            // 64 KB
    float*          knp    = (float*)(wsb + 50434048);            // 4 KB
    float*          Mb     = (float*)(wsb + 50438144);            // 64 KB
    float*          zpart  = (float*)(wsb + 50503680);            // 256 KB
    float*          Lp     = (float*)(wsb + 50765824);            // 16 KB
    // gemm-phase temporaries overlay the dsum region (dead before pvds)
    unsigned short* Hhi    = (unsigned short*)(wsb + 8388608);    // 4 MB
    unsigned short* Hlo    = (unsigned short*)(wsb + 12582912);   // 4 MB
    unsigned short* WhbHi  = (unsigned short*)(wsb + 16777216);   // 2 MB
    unsigned short* WhbLo  = (unsigned short*)(wsb + 18874368);   // 2 MB
    unsigned short* Whi    = (unsigned short*)(wsb + 20971520);   // 256 KB
    unsigned short* Wlo    = (unsigned short*)(wsb + 21233664);
    unsigned short* Qhi    = (unsigned short*)(wsb + 21495808);   // 384 KB
    unsigned short* Qlo    = (unsigned short*)(wsb + 21889024);
    unsigned short* WLhi   = (unsigned short*)(wsb + 22282240);   // 128 KB
    unsigned short* WLlo   = (unsigned short*)(wsb + 22413312);
    unsigned short* WcThi  = (unsigned short*)(wsb + 22544384);   // 256 KB
    unsigned short* WcTlo  = (unsigned short*)(wsb + 22806528);

    hipMemsetAsync(pacc_f, 0, 4194304, stream);
    hipMemsetAsync(wacc_f, 0, 4194304, stream);
    hipMemsetAsync(Lp, 0, 16384, stream);

    dim3 blk(256);
    wprep<<<dim3(2048), blk, 0, stream>>>(W, Wqkv_w, Wl_w, h,
        Whi, Wlo, Qhi, Qlo, WLhi, WLlo, Hhi, Hlo);
    // WcT[256][512] = Wl_w @ W^T (bf16 hi/lo)
    gemm_mfma<3, false><<<dim3(8, 4), blk, 0, stream>>>(
        WLhi, WLlo, Whi, Wlo, nullptr, WcThi, WcTlo, nullptr, 256, 512, 256);
    // Wh = h @ WcT^T + Wl_b  -> Whb hi/lo + WhT bf16
    gemm_mfma<1, true><<<dim3(4, 64), blk, 0, stream>>>(
        Hhi, Hlo, WcThi, WcTlo, Wl_b, WhbHi, WhbLo, wht, 4096, 256, 512);
    // qkv = Wh @ Wqkv_w^T + Wqkv_b -> q,k row bf16 + vT
    gemm_mfma<2, true><<<dim3(12, 64), blk, 0, stream>>>(
        WhbHi, WhbLo, Qhi, Qlo, Wqkv_b, qh, kh, vth, 4096, 768, 256);
    compute_p<<<dim3(256), blk, 0, stream>>>(WhbHi, WhbLo, a, p1b, p2b);
    p2max_kernel<<<dim3(1), blk, 0, stream>>>(p2b, p2m);
    norms1<<<dim3(256), blk, 0, stream>>>(qh, kh, qn2, knp);
    norms2<<<dim3(16), blk, 0, stream>>>(qn2, knp, Mb);
    zsum_kernel<<<dim3(1024), blk, 0, stream>>>(qh, kh, Mb, zpart);
    pvds_kernel<<<dim3(1024), blk, 0, stream>>>(qh, kh, vth, Mb, zpart, dsum_b, pacc_f);
    outer_kernel<<<dim3(1024), blk, 0, stream>>>(wht, dsum_b, p1b, p2b, p2m, adj, wacc_f, Lp);
    merge_kernel<<<dim3(256), blk, 0, stream>>>(pacc_f, wacc_f, Lp, out);
}